// Round 7
// baseline (2068.249 us; speedup 1.0000x reference)
//
#include <hip/hip_runtime.h>

// Furthest Point Sampling, B=8, C=3, N=65536, NUM_POINTS=1024.
//
// R7: measured XCD placement + barrier-free main loop.
//
//  Placement (init, once): 256 blocks launched. Each block reads its physical
//  XCD id via s_getreg(HW_REG_XCC_ID) [HW-verified on MI355X], registers on a
//  per-XCD counter. First 16 registrants on XCD j own batch j (slice = rank) --
//  so the batch's writers and pollers are PROVABLY on one XCD and the sc0 L2
//  exchange is genuinely XCD-local. Blocks beyond 16 become spares: they wait
//  until all 256 blocks registered (wait-free: every block increments 'done'
//  unconditionally, actives never wait => no deadlock possible), then cover any
//  vacancies deterministically (rank -> lexicographic vacancy). Spare-covered
//  slices run cross-XCD and are carried by the agent/IC fallback line -- slow
//  but correct. Normally there are zero vacancies.
//
//  Main loop (NO barriers, no intra-block reduce on the critical path):
//   1. register dist update + per-thread argmax (16 reg-resident pts/thread),
//   2. wave butterfly -> each WAVE publishes its key to its own slot:
//      line A (sc0 store, XCD-local L2) + line B (agent store, IC fallback),
//   3. wave 0 polls all 64 wave-slots (16 slices x 4 waves) -- 64 lanes = one
//      dwordx2 load round -- merging IC fallback words on late rounds, then a
//      6-step butterfly yields the global winner; fans out via a tagged
//      parity-double-buffered LDS mailbox to waves 1-3,
//   4. winner coords via readfirstlane'd scalar loads (XCD-L2 resident).
//  Region reuse depth 16 with tag validation (key low 16 bits == it): a wave
//  enters it+1 only after every wave of every block published it, so skew < 2
//  iterations << 16; 0xAA poison (tag 0xAAAA) never matches it < 1024 -> no
//  slot memset (only the 40B control block is zeroed per launch).
//
// Key packing (idx < 65536): dist_bits(32) | (0xFFFF - idx)(16) | it(16).
// Max key = max dist, tie -> smaller index == jnp.argmax first-occurrence
// (dist >= 0 -> float bits monotone; same tag on all keys of an iteration).
// Distance math: __fmul_rn/__fadd_rn (no FMA contraction) to bit-match numpy.

namespace {

constexpr int kB = 8;
constexpr int kN = 65536;
constexpr int kNP = 1024;
constexpr int kPB = 16;                      // slices (blocks) per batch
constexpr int kThreads = 256;
constexpr int kPPT = kN / (kPB * kThreads);  // 16 points per thread
constexpr int kGrp = kPPT / 4;               // 4 float4 groups
constexpr int kWaves = kThreads / 64;        // 4
constexpr int kSlots = kPB * kWaves;         // 64 wave-slots per batch-iteration
constexpr int kRgn = 16;                     // region reuse depth (skew < 2)
constexpr int kRgnStride = 2 * kSlots;       // u64s: [0:64)=line A, [64:128)=line B
constexpr int kBlocks = 256;                 // launched blocks (spares cover vacancies)

__device__ __forceinline__ unsigned long long shfl_xor_u64(unsigned long long v, int off) {
  return (unsigned long long)__shfl_xor((long long)v, off, 64);
}

__device__ __forceinline__ unsigned long long u64max(unsigned long long a,
                                                     unsigned long long b) {
  return a > b ? a : b;
}

// sc0 load: bypass L1, served by this XCD's L2 (the intra-XCD coherence point).
__device__ __forceinline__ unsigned long long load_l2(const unsigned long long* p) {
  unsigned long long v;
  asm volatile("global_load_dwordx2 %0, %1, off sc0\n\ts_waitcnt vmcnt(0)"
               : "=v"(v)
               : "v"(p)
               : "memory");
  return v;
}

// sc0 store: write-through to this XCD's L2.
__device__ __forceinline__ void store_l2(unsigned long long* p, unsigned long long v) {
  asm volatile("global_store_dwordx2 %0, %1, off sc0" ::"v"(p), "v"(v) : "memory");
}

__global__ __launch_bounds__(kThreads) void fps_kernel(const float* __restrict__ pts,
                                                       float* __restrict__ out,
                                                       unsigned long long* __restrict__ slots,
                                                       unsigned* __restrict__ ctrl) {
  // ctrl layout: [0:8) per-XCD registration counters, [8] done, [9] spare rank.
  const int tid = threadIdx.x;
  const int lane = tid & 63;
  const int wave = tid >> 6;

  __shared__ int s_batch, s_slice;
  __shared__ unsigned s_win[2];  // parity mailbox: (wi << 16) | it
  __shared__ int s_hist[kNP];

  if (tid == 0) {
    unsigned xcc;
    asm volatile("s_getreg_b32 %0, hwreg(HW_REG_XCC_ID)" : "=s"(xcc));
    const int home = (int)(xcc & 7u);
    int batch = -1, slice = -1;
    const int pos = (int)atomicAdd(&ctrl[home], 1u);
    if (pos < kPB) {
      batch = home;
      slice = pos;
    }
    __hip_atomic_fetch_add(&ctrl[8], 1u, __ATOMIC_RELEASE, __HIP_MEMORY_SCOPE_AGENT);
    if (batch < 0) {
      // Spare: wait for all registrations (every block increments 'done'
      // unconditionally => bounded wait, no deadlock), then cover a vacancy.
      while (__hip_atomic_load(&ctrl[8], __ATOMIC_ACQUIRE, __HIP_MEMORY_SCOPE_AGENT) <
             (unsigned)kBlocks) {
        __builtin_amdgcn_s_sleep(8);
      }
      int need = (int)atomicAdd(&ctrl[9], 1u);
      for (int j = 0; j < kB; ++j) {
        int have = (int)__hip_atomic_load(&ctrl[j], __ATOMIC_RELAXED, __HIP_MEMORY_SCOPE_AGENT);
        have = have > kPB ? kPB : have;
        const int vac = kPB - have;
        if (need < vac) {
          batch = j;
          slice = have + need;
          break;
        }
        need -= vac;
      }
    }
    s_batch = batch;
    s_slice = slice;
    s_win[0] = 0xFFFFFFFFu;  // tag 0xFFFF never matches it < 1024
    s_win[1] = 0xFFFFFFFFu;
  }
  __syncthreads();

  const int batch = s_batch;
  const int slice = s_slice;
  if (batch < 0) return;  // unneeded spare

  const float* __restrict__ xb = pts + (size_t)batch * 3 * kN;
  const float* __restrict__ yb = xb + kN;
  const float* __restrict__ zb = xb + 2 * kN;

  // Register-resident coords: block owns [slice*4096, slice*4096+4096).
  const int sbase = slice * (kThreads * kPPT);
  const int base0 = sbase + tid * 4;
  float px[kPPT], py[kPPT], pz[kPPT], dist[kPPT];
#pragma unroll
  for (int g = 0; g < kGrp; ++g) {
    const int base = base0 + g * (kThreads * 4);
    const float4 vx = *reinterpret_cast<const float4*>(xb + base);
    const float4 vy = *reinterpret_cast<const float4*>(yb + base);
    const float4 vz = *reinterpret_cast<const float4*>(zb + base);
    px[g * 4 + 0] = vx.x; px[g * 4 + 1] = vx.y; px[g * 4 + 2] = vx.z; px[g * 4 + 3] = vx.w;
    py[g * 4 + 0] = vy.x; py[g * 4 + 1] = vy.y; py[g * 4 + 2] = vy.z; py[g * 4 + 3] = vy.w;
    pz[g * 4 + 0] = vz.x; pz[g * 4 + 1] = vz.y; pz[g * 4 + 2] = vz.z; pz[g * 4 + 3] = vz.w;
  }
#pragma unroll
  for (int k = 0; k < kPPT; ++k) dist[k] = 1e10f;

  // Seed: index 0 (uniform broadcast load).
  float qx = xb[0], qy = yb[0], qz = zb[0];

  unsigned long long* const sb = slots + (size_t)batch * kRgn * kRgnStride;
  const int wslot = slice * kWaves + wave;  // this wave's slot, 0..63

  for (int it = 1; it < kNP; ++it) {
    // --- update dists + per-thread argmax (ascending index, strict '>') ---
    float bd = -1.0f;
    int bi = 0;
#pragma unroll
    for (int g = 0; g < kGrp; ++g) {
#pragma unroll
      for (int j = 0; j < 4; ++j) {
        const int k = g * 4 + j;
        const float dx = px[k] - qx;
        const float dy = py[k] - qy;
        const float dz = pz[k] - qz;
        const float ss =
            __fadd_rn(__fadd_rn(__fmul_rn(dx, dx), __fmul_rn(dy, dy)), __fmul_rn(dz, dz));
        const float nd = fminf(dist[k], ss);
        dist[k] = nd;
        if (nd > bd) {
          bd = nd;
          bi = base0 + g * (kThreads * 4) + j;
        }
      }
    }

    // key: dist(32) | (0xFFFF - idx)(16) | it(16)  -- tag self-validates slots.
    unsigned long long key = ((unsigned long long)__float_as_uint(bd) << 32) |
                             ((unsigned long long)(0xFFFFu - (unsigned)bi) << 16) |
                             (unsigned long long)(unsigned)it;

    // --- wave butterfly, then the wave publishes ITS key (no block reduce) ---
#pragma unroll
    for (int off = 32; off > 0; off >>= 1) {
      key = u64max(key, shfl_xor_u64(key, off));
    }
    unsigned long long* const rgn = sb + (size_t)(it & (kRgn - 1)) * kRgnStride;
    if (lane == 0) {
      store_l2(rgn + wslot, key);  // fast path: XCD-local L2
      __hip_atomic_store(rgn + kSlots + wslot, key, __ATOMIC_RELAXED,
                         __HIP_MEMORY_SCOPE_AGENT);  // correctness path: IC
    }

    int wi;
    if (wave == 0) {
      // --- poll 64 wave-slots: 64 lanes = one load round per attempt ---
      unsigned long long w;
      int round = 0;
      for (;;) {
        unsigned long long a = load_l2(rgn + lane);
        bool ok = (unsigned)(a & 0xFFFFull) == (unsigned)it;
        if (round >= 3 && (round & 1)) {
          const unsigned long long fb = __hip_atomic_load(rgn + kSlots + lane, __ATOMIC_RELAXED,
                                                          __HIP_MEMORY_SCOPE_AGENT);
          if (!ok && (unsigned)(fb & 0xFFFFull) == (unsigned)it) {
            a = fb;
            ok = true;
          }
        }
        if (__all(ok)) {
          w = a;
          break;
        }
        ++round;
      }
      // 6-step butterfly over the 64 slots.
#pragma unroll
      for (int off = 1; off < kSlots; off <<= 1) {
        w = u64max(w, shfl_xor_u64(w, off));
      }
      wi = (int)(0xFFFFu - ((unsigned)(w >> 16) & 0xFFFFu));
      if (lane == 0) {
        s_hist[it] = wi;
        __hip_atomic_store(&s_win[it & 1], ((unsigned)wi << 16) | (unsigned)it,
                           __ATOMIC_RELAXED, __HIP_MEMORY_SCOPE_WORKGROUP);
      }
    } else {
      // --- non-leader waves: spin on the LDS mailbox (no global traffic) ---
      unsigned v;
      do {
        v = __hip_atomic_load(&s_win[it & 1], __ATOMIC_RELAXED, __HIP_MEMORY_SCOPE_WORKGROUP);
      } while ((v & 0xFFFFu) != (unsigned)it);
      wi = (int)(v >> 16);
    }

    // Winner coords: uniform scalar loads (points are XCD-L2 resident).
    const int wiu = __builtin_amdgcn_readfirstlane(wi);
    qx = xb[wiu];
    qy = yb[wiu];
    qz = zb[wiu];
  }

  __syncthreads();  // make s_hist (written by wave 0) visible to all waves

  // --- gather: out[b][c][j] = points[b][c][idx_j]; slice-0 block per batch ---
  if (slice == 0) {
    float* __restrict__ ob = out + (size_t)batch * 3 * kNP;
    for (int j = tid; j < kNP; j += kThreads) {
      const int id = (j == 0) ? 0 : s_hist[j];
      ob[j] = xb[id];
      ob[kNP + j] = yb[id];
      ob[2 * kNP + j] = zb[id];
    }
  }
}

}  // namespace

extern "C" void kernel_launch(void* const* d_in, const int* in_sizes, int n_in,
                              void* d_out, int out_size, void* d_ws, size_t ws_size,
                              hipStream_t stream) {
  (void)in_sizes;
  (void)n_in;
  (void)out_size;
  (void)ws_size;
  const float* pts = (const float*)d_in[0];
  float* out = (float*)d_out;
  // ws: [0,256) control block (zeroed), [1024, 1024+128K) slot regions
  // (tag-validated: 0xAA poison -> tag 0xAAAA never equals it < 1024 -> no memset).
  unsigned* ctrl = (unsigned*)d_ws;
  unsigned long long* slots = (unsigned long long*)((char*)d_ws + 1024);
  hipMemsetAsync(d_ws, 0, 256, stream);
  fps_kernel<<<dim3(kBlocks), dim3(kThreads), 0, stream>>>(pts, out, slots, ctrl);
}

// Round 8
// 1720.742 us; speedup vs baseline: 1.2020x; 1.2020x over previous
//
#include <hip/hip_runtime.h>

// Furthest Point Sampling, B=8, C=3, N=65536, NUM_POINTS=1024.
//
// R8 = R6 skeleton with the exchange stripped to the single proven path.
// Evidence R6/R7: the sc0 "XCD-local L2" fast path never delivered a remote
// block's store in time (fallback IC reads fired every iteration, and the first
// IC check sat at poll round 5 -> ~1200cy/iter of dead polling). So: publish
// ONE agent-scope (IC) store per block, poll the IC line from round 0, every
// round. No dual lines, no placement machinery, no memset.
//
//  - 16 blocks x 256 threads per batch (128 blocks total; blockIdx&7 = batch,
//    which also spreads each batch's points across XCD L2s -- heuristic only).
//  - Each block's 4096 points register-resident (16 pts/thread).
//  - Per iteration: register dist update + per-thread argmax -> wave butterfly
//    -> LDS -> ONE __syncthreads -> wave 0: 4-key block reduce, one 8B
//    agent-scope store to this block's slot (16 slots = one 128B line per
//    batch-iteration), poll all 16 slots (64 lanes, one dwordx2 round per
//    attempt, 4x redundant) until all tags match, 4-step butterfly -> winner.
//    Waves 1-3 get the winner via a tagged parity-double-buffered LDS mailbox
//    (zero global traffic). Winner coords: uniform scalar loads (L2-resident).
//  - Slot regions reused modulo 16 with tag validation (key low 16 == it):
//    a block enters it+1 only after seeing every block's publish of it, so
//    skew < 2 iterations << 16 -> regions quiescent when rewritten. 0xAA ws
//    poison = tag 0xAAAA never matches it < 1024 -> NO memset, no extra dispatch.
//
// Key packing (idx < 65536): dist_bits(32) | (0xFFFF - idx)(16) | it(16).
// Max key = max dist, tie -> smaller index == jnp.argmax first-occurrence
// (dist >= 0 -> float bits monotone; same tag on all keys of an iteration).
// Distance math: __fmul_rn/__fadd_rn (no FMA contraction) to bit-match numpy.

namespace {

constexpr int kB = 8;
constexpr int kN = 65536;
constexpr int kNP = 1024;
constexpr int kPB = 16;                      // blocks per batch (16 slots = one 128B line)
constexpr int kThreads = 256;
constexpr int kPPT = kN / (kPB * kThreads);  // 16 points per thread
constexpr int kGrp = kPPT / 4;               // 4 float4 groups
constexpr int kWaves = kThreads / 64;        // 4
constexpr int kRgn = 16;                     // region reuse depth (skew < 2)

__device__ __forceinline__ unsigned long long shfl_xor_u64(unsigned long long v, int off) {
  return (unsigned long long)__shfl_xor((long long)v, off, 64);
}

__device__ __forceinline__ unsigned long long u64max(unsigned long long a,
                                                     unsigned long long b) {
  return a > b ? a : b;
}

__global__ __launch_bounds__(kThreads) void fps_kernel(const float* __restrict__ pts,
                                                       float* __restrict__ out,
                                                       unsigned long long* __restrict__ slots) {
  const int batch = blockIdx.x & 7;
  const int slice = blockIdx.x >> 3;  // 0..15
  const int tid = threadIdx.x;
  const int lane = tid & 63;
  const int wave = tid >> 6;

  const float* __restrict__ xb = pts + (size_t)batch * 3 * kN;
  const float* __restrict__ yb = xb + kN;
  const float* __restrict__ zb = xb + 2 * kN;

  __shared__ unsigned long long s_wkey[kWaves];
  __shared__ unsigned s_win[2];  // parity mailbox: (wi << 16) | it
  __shared__ int s_hist[kNP];

  if (tid == 0) {
    s_win[0] = 0xFFFFFFFFu;  // tag 0xFFFF never matches it < 1024
    s_win[1] = 0xFFFFFFFFu;
  }

  // Register-resident coords: block owns [slice*4096, slice*4096+4096).
  const int sbase = slice * (kThreads * kPPT);
  const int base0 = sbase + tid * 4;
  float px[kPPT], py[kPPT], pz[kPPT], dist[kPPT];
#pragma unroll
  for (int g = 0; g < kGrp; ++g) {
    const int base = base0 + g * (kThreads * 4);
    const float4 vx = *reinterpret_cast<const float4*>(xb + base);
    const float4 vy = *reinterpret_cast<const float4*>(yb + base);
    const float4 vz = *reinterpret_cast<const float4*>(zb + base);
    px[g * 4 + 0] = vx.x; px[g * 4 + 1] = vx.y; px[g * 4 + 2] = vx.z; px[g * 4 + 3] = vx.w;
    py[g * 4 + 0] = vy.x; py[g * 4 + 1] = vy.y; py[g * 4 + 2] = vy.z; py[g * 4 + 3] = vy.w;
    pz[g * 4 + 0] = vz.x; pz[g * 4 + 1] = vz.y; pz[g * 4 + 2] = vz.z; pz[g * 4 + 3] = vz.w;
  }
#pragma unroll
  for (int k = 0; k < kPPT; ++k) dist[k] = 1e10f;

  // Seed: index 0 (uniform broadcast load).
  float qx = xb[0], qy = yb[0], qz = zb[0];

  unsigned long long* const sb = slots + (size_t)batch * kRgn * kPB;

  for (int it = 1; it < kNP; ++it) {
    // --- update dists + per-thread argmax (ascending index, strict '>') ---
    float bd = -1.0f;
    int bi = 0;
#pragma unroll
    for (int g = 0; g < kGrp; ++g) {
#pragma unroll
      for (int j = 0; j < 4; ++j) {
        const int k = g * 4 + j;
        const float dx = px[k] - qx;
        const float dy = py[k] - qy;
        const float dz = pz[k] - qz;
        const float ss =
            __fadd_rn(__fadd_rn(__fmul_rn(dx, dx), __fmul_rn(dy, dy)), __fmul_rn(dz, dz));
        const float nd = fminf(dist[k], ss);
        dist[k] = nd;
        if (nd > bd) {
          bd = nd;
          bi = base0 + g * (kThreads * 4) + j;
        }
      }
    }

    // key: dist(32) | (0xFFFF - idx)(16) | it(16)  -- tag self-validates slots.
    unsigned long long key = ((unsigned long long)__float_as_uint(bd) << 32) |
                             ((unsigned long long)(0xFFFFu - (unsigned)bi) << 16) |
                             (unsigned long long)(unsigned)it;

    // --- wave butterfly ---
#pragma unroll
    for (int off = 32; off > 0; off >>= 1) {
      key = u64max(key, shfl_xor_u64(key, off));
    }
    if (lane == 0) s_wkey[wave] = key;
    __syncthreads();  // the only barrier in the iteration

    int wi;
    if (wave == 0) {
      // --- block reduce over 4 wave keys ---
      unsigned long long bk = s_wkey[lane & (kWaves - 1)];
#pragma unroll
      for (int off = 1; off < kWaves; off <<= 1) {
        bk = u64max(bk, shfl_xor_u64(bk, off));
      }

      unsigned long long* const rgn = sb + (size_t)(it & (kRgn - 1)) * kPB;
      if (lane == 0) {
        __hip_atomic_store(rgn + slice, bk, __ATOMIC_RELAXED, __HIP_MEMORY_SCOPE_AGENT);
      }

      // --- poll the 16-slot IC line from round 0, every round ---
      unsigned long long w;
      for (;;) {
        w = __hip_atomic_load(rgn + (lane & (kPB - 1)), __ATOMIC_RELAXED,
                              __HIP_MEMORY_SCOPE_AGENT);
        if (__all((unsigned)(w & 0xFFFFull) == (unsigned)it)) break;
      }
      // Reduce 16 slots (lanes hold slot lane&15): 4-step butterfly.
#pragma unroll
      for (int off = 1; off < kPB; off <<= 1) {
        w = u64max(w, shfl_xor_u64(w, off));
      }
      wi = (int)(0xFFFFu - ((unsigned)(w >> 16) & 0xFFFFu));
      if (lane == 0) {
        s_hist[it] = wi;
        __hip_atomic_store(&s_win[it & 1], ((unsigned)wi << 16) | (unsigned)it,
                           __ATOMIC_RELAXED, __HIP_MEMORY_SCOPE_WORKGROUP);
      }
    } else {
      // --- non-leader waves: spin on the LDS mailbox (no global traffic) ---
      unsigned v;
      do {
        v = __hip_atomic_load(&s_win[it & 1], __ATOMIC_RELAXED, __HIP_MEMORY_SCOPE_WORKGROUP);
      } while ((v & 0xFFFFu) != (unsigned)it);
      wi = (int)(v >> 16);
    }

    // Winner coords: uniform scalar loads (points are L2-resident).
    const int wiu = __builtin_amdgcn_readfirstlane(wi);
    qx = xb[wiu];
    qy = yb[wiu];
    qz = zb[wiu];
  }

  __syncthreads();  // make s_hist (written by wave 0) visible to all waves

  // --- gather: out[b][c][j] = points[b][c][idx_j]; slice-0 block per batch ---
  if (slice == 0) {
    float* __restrict__ ob = out + (size_t)batch * 3 * kNP;
    for (int j = tid; j < kNP; j += kThreads) {
      const int id = (j == 0) ? 0 : s_hist[j];
      ob[j] = xb[id];
      ob[kNP + j] = yb[id];
      ob[2 * kNP + j] = zb[id];
    }
  }
}

}  // namespace

extern "C" void kernel_launch(void* const* d_in, const int* in_sizes, int n_in,
                              void* d_out, int out_size, void* d_ws, size_t ws_size,
                              hipStream_t stream) {
  (void)in_sizes;
  (void)n_in;
  (void)out_size;
  (void)ws_size;
  const float* pts = (const float*)d_in[0];
  float* out = (float*)d_out;
  // 8 batches x 16 regions x 16 slots x 8B = 16 KB of d_ws. Tag-validated
  // (0xAA poison -> tag 0xAAAA never equals it < 1024) => NO memset, and
  // region reuse depth 16 >> max block skew (<2 iterations).
  unsigned long long* slots = (unsigned long long*)d_ws;
  fps_kernel<<<dim3(kB * kPB), dim3(kThreads), 0, stream>>>(pts, out, slots);
}

// Round 9
// 1662.004 us; speedup vs baseline: 1.2444x; 1.0353x over previous
//
#include <hip/hip_runtime.h>

// Furthest Point Sampling, B=8, C=3, N=65536, NUM_POINTS=1024.
//
// R9 = R8's minimal exchange + MEASURED XCD placement + XCD-local L2 exchange.
//
// Evidence so far: R3/R6/R8 (all IC-mediated exchanges) are invariant at
// ~1.7us/iter -> the Infinity-Cache store->load RTT is the floor of any
// IC-mediated protocol. R6's L2 fast path failed because %8 placement did NOT
// co-locate (fallback fired every iteration); R7 proved measured placement is
// mechanically sound but confounded the test with 4x publish traffic.
//
//  Placement (init, once): 256 blocks. Each reads its physical XCD id via
//  s_getreg(HW_REG_XCC_ID) and registers on a per-XCD counter; the first 16
//  registrants on XCD j own batch j (slice = rank), so a batch's 16 blocks are
//  PROVABLY on one XCD. Late blocks become spares: wait until all 256 register
//  (every block increments 'done' unconditionally -> bounded wait, no deadlock),
//  then deterministically cover vacancies (normally none); spare-covered slices
//  run cross-XCD on the IC fallback line -- slower but correct. Unneeded spares
//  exit.
//
//  Main loop (per iteration, ONE barrier):
//   1. register dist update + per-thread argmax (16 reg-resident pts/thread),
//   2. wave butterfly -> LDS -> __syncthreads -> wave 0: 4-key block reduce,
//   3. leader publishes the block key to line A (sc0 store -> this XCD's L2,
//      the intra-XCD coherence point) and line B (agent-scope store -> IC),
//   4. wave 0 polls line A (16 slots, 64 lanes, one dwordx2 round / attempt)
//      from round 0; from round 2 it also merges line B words, so progress
//      never depends on placement. 4-step butterfly -> global winner; fans out
//      to waves 1-3 via a tagged parity-double-buffered LDS mailbox,
//   5. winner coords via readfirstlane'd uniform loads (points L2-resident).
//  Regions reused modulo 16, tag-validated (key low 16 bits == it; blocks skew
//  < 2 iterations << 16; 0xAA poison = tag 0xAAAA never matches it < 1024) ->
//  slots need no memset (only the 64B ctrl block is zeroed per launch).
//
// Key packing (idx < 65536): dist_bits(32) | (0xFFFF - idx)(16) | it(16).
// Max key = max dist, tie -> smaller index == jnp.argmax first-occurrence
// (dist >= 0 -> float bits monotone; same tag on all keys of an iteration).
// Distance math: __fmul_rn/__fadd_rn (no FMA contraction) to bit-match numpy.

namespace {

constexpr int kB = 8;
constexpr int kN = 65536;
constexpr int kNP = 1024;
constexpr int kPB = 16;                      // slices (blocks) per batch
constexpr int kThreads = 256;
constexpr int kPPT = kN / (kPB * kThreads);  // 16 points per thread
constexpr int kGrp = kPPT / 4;               // 4 float4 groups
constexpr int kWaves = kThreads / 64;        // 4
constexpr int kRgn = 16;                     // region reuse depth (skew < 2)
constexpr int kRgnStride = 32;               // u64: [0:16)=line A (L2), [16:32)=line B (IC)
constexpr int kBlocks = 256;

__device__ __forceinline__ unsigned long long shfl_xor_u64(unsigned long long v, int off) {
  return (unsigned long long)__shfl_xor((long long)v, off, 64);
}

__device__ __forceinline__ unsigned long long u64max(unsigned long long a,
                                                     unsigned long long b) {
  return a > b ? a : b;
}

// sc0 load: bypass L1, served by this XCD's L2 (the intra-XCD coherence point).
__device__ __forceinline__ unsigned long long load_l2(const unsigned long long* p) {
  unsigned long long v;
  asm volatile("global_load_dwordx2 %0, %1, off sc0\n\ts_waitcnt vmcnt(0)"
               : "=v"(v)
               : "v"(p)
               : "memory");
  return v;
}

// sc0 store: write-through to this XCD's L2.
__device__ __forceinline__ void store_l2(unsigned long long* p, unsigned long long v) {
  asm volatile("global_store_dwordx2 %0, %1, off sc0" ::"v"(p), "v"(v) : "memory");
}

__global__ __launch_bounds__(kThreads) void fps_kernel(const float* __restrict__ pts,
                                                       float* __restrict__ out,
                                                       unsigned long long* __restrict__ slots,
                                                       unsigned* __restrict__ ctrl) {
  // ctrl: [0:8) per-XCD registration counters, [8] done count, [9] spare rank.
  const int tid = threadIdx.x;
  const int lane = tid & 63;
  const int wave = tid >> 6;

  __shared__ int s_batch, s_slice;
  __shared__ unsigned long long s_wkey[kWaves];
  __shared__ unsigned s_win[2];  // parity mailbox: (wi << 16) | it
  __shared__ int s_hist[kNP];

  if (tid == 0) {
    unsigned xcc;
    asm volatile("s_getreg_b32 %0, hwreg(HW_REG_XCC_ID)" : "=s"(xcc));
    const int home = (int)(xcc & 7u);
    int batch = -1, slice = -1;
    const int pos = (int)atomicAdd(&ctrl[home], 1u);
    if (pos < kPB) {
      batch = home;
      slice = pos;
    }
    __hip_atomic_fetch_add(&ctrl[8], 1u, __ATOMIC_RELEASE, __HIP_MEMORY_SCOPE_AGENT);
    if (batch < 0) {
      while (__hip_atomic_load(&ctrl[8], __ATOMIC_ACQUIRE, __HIP_MEMORY_SCOPE_AGENT) <
             (unsigned)kBlocks) {
        __builtin_amdgcn_s_sleep(8);
      }
      int need = (int)atomicAdd(&ctrl[9], 1u);
      for (int j = 0; j < kB; ++j) {
        int have = (int)__hip_atomic_load(&ctrl[j], __ATOMIC_RELAXED, __HIP_MEMORY_SCOPE_AGENT);
        have = have > kPB ? kPB : have;
        const int vac = kPB - have;
        if (need < vac) {
          batch = j;
          slice = have + need;
          break;
        }
        need -= vac;
      }
    }
    s_batch = batch;
    s_slice = slice;
    s_win[0] = 0xFFFFFFFFu;  // tag 0xFFFF never matches it < 1024
    s_win[1] = 0xFFFFFFFFu;
  }
  __syncthreads();

  const int batch = s_batch;
  const int slice = s_slice;
  if (batch < 0) return;  // unneeded spare

  const float* __restrict__ xb = pts + (size_t)batch * 3 * kN;
  const float* __restrict__ yb = xb + kN;
  const float* __restrict__ zb = xb + 2 * kN;

  // Register-resident coords: block owns [slice*4096, slice*4096+4096).
  const int sbase = slice * (kThreads * kPPT);
  const int base0 = sbase + tid * 4;
  float px[kPPT], py[kPPT], pz[kPPT], dist[kPPT];
#pragma unroll
  for (int g = 0; g < kGrp; ++g) {
    const int base = base0 + g * (kThreads * 4);
    const float4 vx = *reinterpret_cast<const float4*>(xb + base);
    const float4 vy = *reinterpret_cast<const float4*>(yb + base);
    const float4 vz = *reinterpret_cast<const float4*>(zb + base);
    px[g * 4 + 0] = vx.x; px[g * 4 + 1] = vx.y; px[g * 4 + 2] = vx.z; px[g * 4 + 3] = vx.w;
    py[g * 4 + 0] = vy.x; py[g * 4 + 1] = vy.y; py[g * 4 + 2] = vy.z; py[g * 4 + 3] = vy.w;
    pz[g * 4 + 0] = vz.x; pz[g * 4 + 1] = vz.y; pz[g * 4 + 2] = vz.z; pz[g * 4 + 3] = vz.w;
  }
#pragma unroll
  for (int k = 0; k < kPPT; ++k) dist[k] = 1e10f;

  // Seed: index 0 (uniform broadcast load).
  float qx = xb[0], qy = yb[0], qz = zb[0];

  unsigned long long* const sb = slots + (size_t)batch * kRgn * kRgnStride;

  for (int it = 1; it < kNP; ++it) {
    // --- update dists + per-thread argmax (ascending index, strict '>') ---
    float bd = -1.0f;
    int bi = 0;
#pragma unroll
    for (int g = 0; g < kGrp; ++g) {
#pragma unroll
      for (int j = 0; j < 4; ++j) {
        const int k = g * 4 + j;
        const float dx = px[k] - qx;
        const float dy = py[k] - qy;
        const float dz = pz[k] - qz;
        const float ss =
            __fadd_rn(__fadd_rn(__fmul_rn(dx, dx), __fmul_rn(dy, dy)), __fmul_rn(dz, dz));
        const float nd = fminf(dist[k], ss);
        dist[k] = nd;
        if (nd > bd) {
          bd = nd;
          bi = base0 + g * (kThreads * 4) + j;
        }
      }
    }

    // key: dist(32) | (0xFFFF - idx)(16) | it(16)  -- tag self-validates slots.
    unsigned long long key = ((unsigned long long)__float_as_uint(bd) << 32) |
                             ((unsigned long long)(0xFFFFu - (unsigned)bi) << 16) |
                             (unsigned long long)(unsigned)it;

    // --- wave butterfly ---
#pragma unroll
    for (int off = 32; off > 0; off >>= 1) {
      key = u64max(key, shfl_xor_u64(key, off));
    }
    if (lane == 0) s_wkey[wave] = key;
    __syncthreads();  // the only barrier in the iteration

    int wi;
    if (wave == 0) {
      // --- block reduce over 4 wave keys ---
      unsigned long long bk = s_wkey[lane & (kWaves - 1)];
#pragma unroll
      for (int off = 1; off < kWaves; off <<= 1) {
        bk = u64max(bk, shfl_xor_u64(bk, off));
      }

      unsigned long long* const rgn = sb + (size_t)(it & (kRgn - 1)) * kRgnStride;
      if (lane == 0) {
        store_l2(rgn + slice, bk);  // primary: XCD-local L2 (measured co-location)
        __hip_atomic_store(rgn + kPB + slice, bk, __ATOMIC_RELAXED,
                           __HIP_MEMORY_SCOPE_AGENT);  // fallback: IC
      }

      // --- poll line A from round 0; merge IC line B from round 2 ---
      unsigned long long w;
      int round = 0;
      for (;;) {
        unsigned long long a = load_l2(rgn + (lane & (kPB - 1)));
        bool ok = (unsigned)(a & 0xFFFFull) == (unsigned)it;
        if (round >= 2 && !ok) {
          const unsigned long long fb = __hip_atomic_load(
              rgn + kPB + (lane & (kPB - 1)), __ATOMIC_RELAXED, __HIP_MEMORY_SCOPE_AGENT);
          if ((unsigned)(fb & 0xFFFFull) == (unsigned)it) {
            a = fb;
            ok = true;
          }
        }
        if (__all(ok)) {
          w = a;
          break;
        }
        ++round;
      }
      // Reduce 16 slots (lanes hold slot lane&15): 4-step butterfly.
#pragma unroll
      for (int off = 1; off < kPB; off <<= 1) {
        w = u64max(w, shfl_xor_u64(w, off));
      }
      wi = (int)(0xFFFFu - ((unsigned)(w >> 16) & 0xFFFFu));
      if (lane == 0) {
        s_hist[it] = wi;
        __hip_atomic_store(&s_win[it & 1], ((unsigned)wi << 16) | (unsigned)it,
                           __ATOMIC_RELAXED, __HIP_MEMORY_SCOPE_WORKGROUP);
      }
    } else {
      // --- non-leader waves: spin on the LDS mailbox (no global traffic) ---
      unsigned v;
      do {
        v = __hip_atomic_load(&s_win[it & 1], __ATOMIC_RELAXED, __HIP_MEMORY_SCOPE_WORKGROUP);
      } while ((v & 0xFFFFu) != (unsigned)it);
      wi = (int)(v >> 16);
    }

    // Winner coords: uniform scalar loads (points are L2-resident).
    const int wiu = __builtin_amdgcn_readfirstlane(wi);
    qx = xb[wiu];
    qy = yb[wiu];
    qz = zb[wiu];
  }

  __syncthreads();  // make s_hist (written by wave 0) visible to all waves

  // --- gather: out[b][c][j] = points[b][c][idx_j]; slice-0 block per batch ---
  if (slice == 0) {
    float* __restrict__ ob = out + (size_t)batch * 3 * kNP;
    for (int j = tid; j < kNP; j += kThreads) {
      const int id = (j == 0) ? 0 : s_hist[j];
      ob[j] = xb[id];
      ob[kNP + j] = yb[id];
      ob[2 * kNP + j] = zb[id];
    }
  }
}

}  // namespace

extern "C" void kernel_launch(void* const* d_in, const int* in_sizes, int n_in,
                              void* d_out, int out_size, void* d_ws, size_t ws_size,
                              hipStream_t stream) {
  (void)in_sizes;
  (void)n_in;
  (void)out_size;
  (void)ws_size;
  const float* pts = (const float*)d_in[0];
  float* out = (float*)d_out;
  // ws: [0,64) ctrl (zeroed per launch), [1024, 1024+32K) slot regions
  // (tag-validated: 0xAA poison -> tag 0xAAAA never equals it < 1024 -> no memset).
  unsigned* ctrl = (unsigned*)d_ws;
  unsigned long long* slots = (unsigned long long*)((char*)d_ws + 1024);
  hipMemsetAsync(d_ws, 0, 64, stream);
  fps_kernel<<<dim3(kBlocks), dim3(kThreads), 0, stream>>>(pts, out, slots, ctrl);
}